// Round 1
// baseline (496.987 us; speedup 1.0000x reference)
//
#include <hip/hip_runtime.h>
#include <math.h>

// Problem constants
#define BATCH 16
#define CH    256
#define CRR   16      // reduced channels
#define HWSZ  16384   // 128*128

// ---------------------------------------------------------------------------
// Kernel 1: global average pool. One block per (b,c) plane (4096 blocks).
// Each plane is 16384 contiguous fp32 = 4096 float4. 256 threads x 16 iters.
// ---------------------------------------------------------------------------
__global__ __launch_bounds__(256) void pool_kernel(const float* __restrict__ x,
                                                   float* __restrict__ pooled) {
    const int bc = blockIdx.x;
    const int t  = threadIdx.x;
    const float4* plane = reinterpret_cast<const float4*>(x + (size_t)bc * HWSZ);

    float sum = 0.0f;
#pragma unroll
    for (int k = 0; k < 16; ++k) {
        float4 v = plane[k * 256 + t];
        sum += (v.x + v.y) + (v.z + v.w);
    }

    // wave (64-lane) reduction
#pragma unroll
    for (int off = 32; off > 0; off >>= 1)
        sum += __shfl_down(sum, off, 64);

    __shared__ float part[4];
    const int lane = t & 63;
    const int wid  = t >> 6;
    if (lane == 0) part[wid] = sum;
    __syncthreads();
    if (t == 0) {
        float tot = (part[0] + part[1]) + (part[2] + part[3]);
        pooled[bc] = tot * (1.0f / 16384.0f);
    }
}

// ---------------------------------------------------------------------------
// Kernel 2: the two tiny FCs + leaky relu + sigmoid. One block per batch.
// ---------------------------------------------------------------------------
__global__ __launch_bounds__(256) void fc_kernel(const float* __restrict__ pooled,
                                                 const float* __restrict__ w1,  // [CRR][CH]
                                                 const float* __restrict__ b1,  // [CRR]
                                                 const float* __restrict__ w2,  // [CH][CRR]
                                                 const float* __restrict__ b2,  // [CH]
                                                 float* __restrict__ s_out) {
    const int b = blockIdx.x;       // 0..15
    const int t = threadIdx.x;      // 0..255

    __shared__ float p_lds[CH];
    __shared__ float h_lds[CRR];

    p_lds[t] = pooled[b * CH + t];
    __syncthreads();

    // h[r] = leaky( b1[r] + dot(pooled[b,:], w1[r,:]) )
    // thread t: r = t>>4 (0..15), seg = t&15 covers 16 channels
    {
        const int r   = t >> 4;
        const int seg = t & 15;
        const float* wrow = w1 + r * CH + seg * 16;
        const float* pp   = p_lds + seg * 16;
        float part_sum = 0.0f;
#pragma unroll
        for (int j = 0; j < 16; ++j)
            part_sum += pp[j] * wrow[j];
        // reduce across the 16 contiguous lanes of this segment group
#pragma unroll
        for (int m = 8; m > 0; m >>= 1)
            part_sum += __shfl_xor(part_sum, m, 64);
        if (seg == 0) {
            float h = part_sum + b1[r];
            h_lds[r] = (h >= 0.0f) ? h : 0.01f * h;
        }
    }
    __syncthreads();

    // s[b,c] = sigmoid( b2[c] + dot(h, w2[c,:]) ), thread t handles c = t
    {
        const int c = t;
        const float* wcol = w2 + c * CRR;
        float z = b2[c];
#pragma unroll
        for (int r = 0; r < CRR; ++r)
            z += h_lds[r] * wcol[r];
        s_out[b * CH + c] = 1.0f / (1.0f + expf(-z));
    }
}

// ---------------------------------------------------------------------------
// Kernel 3: out = x * s[b,c].  One block per (b,c) plane, float4 streaming.
// ---------------------------------------------------------------------------
__global__ __launch_bounds__(256) void scale_kernel(const float* __restrict__ x,
                                                    const float* __restrict__ s,
                                                    float* __restrict__ out) {
    const int bc = blockIdx.x;
    const int t  = threadIdx.x;
    const float sc = s[bc];   // same address per block -> HW broadcast
    const float4* xin = reinterpret_cast<const float4*>(x + (size_t)bc * HWSZ);
    float4*       o   = reinterpret_cast<float4*>(out + (size_t)bc * HWSZ);
#pragma unroll
    for (int k = 0; k < 16; ++k) {
        float4 v = xin[k * 256 + t];
        v.x *= sc; v.y *= sc; v.z *= sc; v.w *= sc;
        o[k * 256 + t] = v;
    }
}

extern "C" void kernel_launch(void* const* d_in, const int* in_sizes, int n_in,
                              void* d_out, int out_size, void* d_ws, size_t ws_size,
                              hipStream_t stream) {
    const float* x  = (const float*)d_in[0];   // [16,256,128,128]
    const float* w1 = (const float*)d_in[1];   // [16,256]
    const float* b1 = (const float*)d_in[2];   // [16]
    const float* w2 = (const float*)d_in[3];   // [256,16]
    const float* b2 = (const float*)d_in[4];   // [256]
    float* out = (float*)d_out;

    float* pooled = (float*)d_ws;              // 4096 floats
    float* s      = pooled + BATCH * CH;       // 4096 floats

    pool_kernel<<<BATCH * CH, 256, 0, stream>>>(x, pooled);
    fc_kernel<<<BATCH, 256, 0, stream>>>(pooled, w1, b1, w2, b2, s);
    scale_kernel<<<BATCH * CH, 256, 0, stream>>>(x, s, out);
}

// Round 5
// 494.634 us; speedup vs baseline: 1.0048x; 1.0048x over previous
//
#include <hip/hip_runtime.h>
#include <math.h>

// Problem constants
#define BATCH 16
#define CH    256
#define CRR   16      // reduced channels
#define HWSZ  16384   // 128*128

// ---------------------------------------------------------------------------
// Kernel 1: global average pool. One block per (b,c) plane (4096 blocks).
// Each plane is 16384 contiguous fp32 = 4096 float4. 256 threads x 16 iters.
// ---------------------------------------------------------------------------
__global__ __launch_bounds__(256) void pool_kernel(const float* __restrict__ x,
                                                   float* __restrict__ pooled) {
    const int bc = blockIdx.x;
    const int t  = threadIdx.x;
    const float4* plane = reinterpret_cast<const float4*>(x + (size_t)bc * HWSZ);

    float sum = 0.0f;
#pragma unroll
    for (int k = 0; k < 16; ++k) {
        float4 v = plane[k * 256 + t];
        sum += (v.x + v.y) + (v.z + v.w);
    }

    // wave (64-lane) reduction
#pragma unroll
    for (int off = 32; off > 0; off >>= 1)
        sum += __shfl_down(sum, off, 64);

    __shared__ float part[4];
    const int lane = t & 63;
    const int wid  = t >> 6;
    if (lane == 0) part[wid] = sum;
    __syncthreads();
    if (t == 0) {
        float tot = (part[0] + part[1]) + (part[2] + part[3]);
        pooled[bc] = tot * (1.0f / 16384.0f);
    }
}

// ---------------------------------------------------------------------------
// Kernel 2: fc (recomputed per block, trivial) + scale. One block per plane.
//   - stage pooled[b,:] in LDS
//   - h[16] via 16-lane segmented dot (w1 is 16 KB -> L2-resident)
//   - each thread computes its plane's gate s = sigmoid(b2[c] + h.w2[c,:])
//   - stream the 64 KiB plane: out = x * s
// ---------------------------------------------------------------------------
__global__ __launch_bounds__(256) void scale_kernel(const float* __restrict__ x,
                                                    const float* __restrict__ pooled,
                                                    const float* __restrict__ w1,  // [CRR][CH]
                                                    const float* __restrict__ b1,  // [CRR]
                                                    const float* __restrict__ w2,  // [CH][CRR]
                                                    const float* __restrict__ b2,  // [CH]
                                                    float* __restrict__ out) {
    const int bc = blockIdx.x;      // plane index
    const int t  = threadIdx.x;
    const int b  = bc >> 8;         // batch
    const int c  = bc & 255;        // channel

    __shared__ float p_lds[CH];
    __shared__ float h_lds[CRR];

    p_lds[t] = pooled[b * CH + t];
    __syncthreads();

    // h[r] = leaky( b1[r] + dot(pooled[b,:], w1[r,:]) )
    {
        const int r   = t >> 4;     // 0..15
        const int seg = t & 15;     // position within 16-lane segment
        const float* wrow = w1 + r * CH + seg * 16;
        const float* pp   = p_lds + seg * 16;
        float ps = 0.0f;
#pragma unroll
        for (int j = 0; j < 16; ++j)
            ps += pp[j] * wrow[j];
#pragma unroll
        for (int m = 8; m > 0; m >>= 1)
            ps += __shfl_xor(ps, m, 64);
        if (seg == 0) {
            float h = ps + b1[r];
            h_lds[r] = (h >= 0.0f) ? h : 0.01f * h;
        }
    }
    __syncthreads();

    // every thread redundantly computes this plane's gate (16 FMA + exp)
    float z = b2[c];
    {
        const float* wcol = w2 + c * CRR;
#pragma unroll
        for (int r = 0; r < CRR; ++r)
            z += h_lds[r] * wcol[r];
    }
    const float sc = 1.0f / (1.0f + expf(-z));

    // stream the plane
    const float4* xin = reinterpret_cast<const float4*>(x + (size_t)bc * HWSZ);
    float4*       o   = reinterpret_cast<float4*>(out + (size_t)bc * HWSZ);
#pragma unroll
    for (int k = 0; k < 16; ++k) {
        float4 v = xin[k * 256 + t];
        v.x *= sc; v.y *= sc; v.z *= sc; v.w *= sc;
        o[k * 256 + t] = v;
    }
}

extern "C" void kernel_launch(void* const* d_in, const int* in_sizes, int n_in,
                              void* d_out, int out_size, void* d_ws, size_t ws_size,
                              hipStream_t stream) {
    const float* x  = (const float*)d_in[0];   // [16,256,128,128]
    const float* w1 = (const float*)d_in[1];   // [16,256]
    const float* b1 = (const float*)d_in[2];   // [16]
    const float* w2 = (const float*)d_in[3];   // [256,16]
    const float* b2 = (const float*)d_in[4];   // [256]
    float* out    = (float*)d_out;
    float* pooled = (float*)d_ws;              // 4096 floats

    pool_kernel<<<BATCH * CH, 256, 0, stream>>>(x, pooled);
    scale_kernel<<<BATCH * CH, 256, 0, stream>>>(x, pooled, w1, b1, w2, b2, out);
}

// Round 7
// 480.129 us; speedup vs baseline: 1.0351x; 1.0302x over previous
//
#include <hip/hip_runtime.h>
#include <math.h>

// Problem constants
#define BATCH 16
#define CH    256
#define CRR   16      // reduced channels
#define HWSZ  16384   // 128*128

// native vector type (ext_vector) — accepted by __builtin_nontemporal_*
typedef float vfloat4 __attribute__((ext_vector_type(4)));

// ---------------------------------------------------------------------------
// Kernel 1: global average pool. One block per (b,c) plane (4096 blocks).
// Regular (allocating) loads on purpose: we WANT x resident in L3 so the
// scale pass re-read hits cache.
// ---------------------------------------------------------------------------
__global__ __launch_bounds__(256) void pool_kernel(const float* __restrict__ x,
                                                   float* __restrict__ pooled) {
    const int bc = blockIdx.x;
    const int t  = threadIdx.x;
    const vfloat4* plane = reinterpret_cast<const vfloat4*>(x + (size_t)bc * HWSZ);

    float sum = 0.0f;
#pragma unroll
    for (int k = 0; k < 16; ++k) {
        vfloat4 v = plane[k * 256 + t];
        sum += (v.x + v.y) + (v.z + v.w);
    }

    // wave (64-lane) reduction
#pragma unroll
    for (int off = 32; off > 0; off >>= 1)
        sum += __shfl_down(sum, off, 64);

    __shared__ float part[4];
    const int lane = t & 63;
    const int wid  = t >> 6;
    if (lane == 0) part[wid] = sum;
    __syncthreads();
    if (t == 0) {
        float tot = (part[0] + part[1]) + (part[2] + part[3]);
        pooled[bc] = tot * (1.0f / 16384.0f);
    }
}

// ---------------------------------------------------------------------------
// Kernel 2: fc (recomputed per block, trivial) + scale. One block per plane.
// out stores are NON-TEMPORAL so they don't allocate in L2/L3 and don't
// evict x — the x re-read should then hit the Infinity Cache.
// ---------------------------------------------------------------------------
__global__ __launch_bounds__(256) void scale_kernel(const float* __restrict__ x,
                                                    const float* __restrict__ pooled,
                                                    const float* __restrict__ w1,  // [CRR][CH]
                                                    const float* __restrict__ b1,  // [CRR]
                                                    const float* __restrict__ w2,  // [CH][CRR]
                                                    const float* __restrict__ b2,  // [CH]
                                                    float* __restrict__ out) {
    const int bc = blockIdx.x;      // plane index
    const int t  = threadIdx.x;
    const int b  = bc >> 8;         // batch
    const int c  = bc & 255;        // channel

    __shared__ float p_lds[CH];
    __shared__ float h_lds[CRR];

    p_lds[t] = pooled[b * CH + t];
    __syncthreads();

    // h[r] = leaky( b1[r] + dot(pooled[b,:], w1[r,:]) )
    {
        const int r   = t >> 4;     // 0..15
        const int seg = t & 15;     // position within 16-lane segment
        const float* wrow = w1 + r * CH + seg * 16;
        const float* pp   = p_lds + seg * 16;
        float ps = 0.0f;
#pragma unroll
        for (int j = 0; j < 16; ++j)
            ps += pp[j] * wrow[j];
#pragma unroll
        for (int m = 8; m > 0; m >>= 1)
            ps += __shfl_xor(ps, m, 64);
        if (seg == 0) {
            float h = ps + b1[r];
            h_lds[r] = (h >= 0.0f) ? h : 0.01f * h;
        }
    }
    __syncthreads();

    // every thread redundantly computes this plane's gate (16 FMA + exp)
    float z = b2[c];
    {
        const float* wcol = w2 + c * CRR;
#pragma unroll
        for (int r = 0; r < CRR; ++r)
            z += h_lds[r] * wcol[r];
    }
    const float sc = 1.0f / (1.0f + expf(-z));

    // stream the plane; non-temporal stores (no cache allocation)
    const vfloat4* xin = reinterpret_cast<const vfloat4*>(x + (size_t)bc * HWSZ);
    vfloat4*       o   = reinterpret_cast<vfloat4*>(out + (size_t)bc * HWSZ);
#pragma unroll
    for (int k = 0; k < 16; ++k) {
        vfloat4 v = xin[k * 256 + t];
        v *= sc;
        __builtin_nontemporal_store(v, &o[k * 256 + t]);
    }
}

extern "C" void kernel_launch(void* const* d_in, const int* in_sizes, int n_in,
                              void* d_out, int out_size, void* d_ws, size_t ws_size,
                              hipStream_t stream) {
    const float* x  = (const float*)d_in[0];   // [16,256,128,128]
    const float* w1 = (const float*)d_in[1];   // [16,256]
    const float* b1 = (const float*)d_in[2];   // [16]
    const float* w2 = (const float*)d_in[3];   // [256,16]
    const float* b2 = (const float*)d_in[4];   // [256]
    float* out    = (float*)d_out;
    float* pooled = (float*)d_ws;              // 4096 floats

    pool_kernel<<<BATCH * CH, 256, 0, stream>>>(x, pooled);
    scale_kernel<<<BATCH * CH, 256, 0, stream>>>(x, pooled, w1, b1, w2, b2, out);
}